// Round 6
// baseline (54.937 us; speedup 1.0000x reference)
//
#include <hip/hip_runtime.h>

// SymmetricContraction (MACE-style), B=128, C=128, E=10, L=16.
// Collapsed to GEMM + Q-fold:
//   D[m,p] = sum_kappa A[m,kappa] * Bm[kappa,p]
//     A1 = U3_1o as [768][528] ++ U2_1o cols (K=544 padded)
//     A0 = U3_0e as [256][368] ++ U2_0e cols (K=384 padded)
//     Bm[kappa=(i,k), p] = x[i,p] * z3[k,p]; U2 rows = z2[k,p]; pad = 0
//   out[group,p] = sum_m Q[m,p]*D[m,p] + z1*U1-term,  Q = x[qa,p]*x[qb,p]
// z*[k,p] = sum_e w*[e][k][c]*y[b][e]  (p = b*128+c)
//
// Round 6: SINGLE kernel (round 5's two-kernel ws handoff read stale/poisoned
// ws under graph replay -> post-timing divergence). A is read directly from
// f32 U3/U2 and packed to bf16 in-register via v_cvt_pk_bf16_f32; K-tail
// synthesized per-lane (lgr 0/1 = U3 tail, lgr2 = U2 row + zeros, lgr3 = 0).
// B built ONCE in LDS (B1[64][552], B0[64][392] bf16), barrier-free MFMA loop.
// 256 blocks x 512 thr, ~141KB LDS, 1 block/CU, 2 waves/SIMD.

typedef float  f32x4  __attribute__((ext_vector_type(4)));
typedef short  short8 __attribute__((ext_vector_type(8)));

namespace {
constexpr int EE  = 10;
constexpr int B1W = 552;   // LDS row shorts (1104B, 16B-aligned)
constexpr int B0W = 392;   // 784B, 16B-aligned
// zbuf row offsets
constexpr int Z31 = 0;   // 33
constexpr int Z21 = 33;  // 6
constexpr int Z11 = 39;  // 1
constexpr int Z30 = 40;  // 23
constexpr int Z20 = 63;  // 4
constexpr int Z10 = 67;  // 1
constexpr int NZ  = 68;
}

__device__ __forceinline__ unsigned cvtpk(float lo, float hi) {
  unsigned r;
  asm("v_cvt_pk_bf16_f32 %0, %1, %2" : "=v"(r) : "v"(lo), "v"(hi));
  return r;
}

__device__ __forceinline__ short8 pack8(float f0, float f1, float f2, float f3,
                                        float f4, float f5, float f6, float f7) {
  union { short8 s; unsigned u[4]; } r;
  r.u[0] = cvtpk(f0, f1);
  r.u[1] = cvtpk(f2, f3);
  r.u[2] = cvtpk(f4, f5);
  r.u[3] = cvtpk(f6, f7);
  return r.s;
}

__global__ __launch_bounds__(512, 2) void symcon_mfma(
    const float* __restrict__ x,      // [B][C][16]
    const float* __restrict__ y,      // [B][E]
    const float* __restrict__ U1_0e,  // [16]
    const float* __restrict__ U2_0e,  // [256][4]
    const float* __restrict__ U3_0e,  // [256][368]
    const float* __restrict__ U1_1o,  // [3][16]
    const float* __restrict__ U2_1o,  // [768][6]
    const float* __restrict__ U3_1o,  // [768][528]
    const float* __restrict__ w1_0e, const float* __restrict__ w2_0e,
    const float* __restrict__ w3_0e, const float* __restrict__ w1_1o,
    const float* __restrict__ w2_1o, const float* __restrict__ w3_1o,
    float* __restrict__ out)          // [B][512]
{
  __shared__ float x_lds[16][64];                 //  4 KB
  __shared__ float zbuf[NZ][64];                  // 17 KB
  __shared__ unsigned short B1buf[64][B1W];       // 69 KB
  __shared__ unsigned short B0buf[64][B0W];       // 49 KB
  __shared__ float red[8][64];                    //  2 KB

  const int tid   = threadIdx.x;
  const int blk   = blockIdx.x;       // 0..255
  const int pair0 = blk * 64;
  const int b     = blk >> 1;         // uniform

  // ---- stage x ----
  for (int t = tid; t < 16 * 64; t += 512) {
    const int i = t >> 6, n = t & 63;
    x_lds[i][n] = x[(size_t)(pair0 + n) * 16 + i];
  }
  // ---- stage z ----
  for (int t = tid; t < NZ * 64; t += 512) {
    const int n  = t & 63;
    const int zi = t >> 6;
    const int c  = ((blk & 1) << 6) + n;
    const float* yb = y + b * EE;
    const float* wsrc; int stride;
    if      (zi < Z21) { wsrc = w3_1o + (zi      ) * 128 + c; stride = 33 * 128; }
    else if (zi < Z11) { wsrc = w2_1o + (zi - Z21) * 128 + c; stride =  6 * 128; }
    else if (zi < Z30) { wsrc = w1_1o +                    c; stride =  1 * 128; }
    else if (zi < Z20) { wsrc = w3_0e + (zi - Z30) * 128 + c; stride = 23 * 128; }
    else if (zi < Z10) { wsrc = w2_0e + (zi - Z20) * 128 + c; stride =  4 * 128; }
    else               { wsrc = w1_0e +                    c; stride =  1 * 128; }
    float a = 0.f;
    #pragma unroll
    for (int e = 0; e < EE; ++e) a += wsrc[e * stride] * yb[e];
    zbuf[zi][n] = a;
  }
  __syncthreads();

  // ---- build ALL of B once (bf16 RNE via cvt_pk) ----
  auto b1valf = [&](int kap, int p) -> float {
    if (kap < 528) { int i = kap / 33, kk = kap - i * 33; return x_lds[i][p] * zbuf[Z31 + kk][p]; }
    if (kap < 534) return zbuf[Z21 + (kap - 528)][p];
    return 0.f;
  };
  auto b0valf = [&](int kap, int p) -> float {
    if (kap < 368) { int i = kap / 23, kk = kap - i * 23; return x_lds[i][p] * zbuf[Z30 + kk][p]; }
    if (kap < 372) return zbuf[Z20 + (kap - 368)][p];
    return 0.f;
  };
  #pragma unroll 1
  for (int idx = tid; idx < 272 * 64; idx += 512) {
    const int p = idx & 63, cp = idx >> 6;     // cp 0..271
    const int k0 = cp * 2;
    *(unsigned*)&B1buf[p][k0] = cvtpk(b1valf(k0, p), b1valf(k0 + 1, p));
  }
  #pragma unroll 1
  for (int idx = tid; idx < 192 * 64; idx += 512) {
    const int p = idx & 63, cp = idx >> 6;     // cp 0..191
    const int k0 = cp * 2;
    *(unsigned*)&B0buf[p][k0] = cvtpk(b0valf(k0, p), b0valf(k0 + 1, p));
  }
  __syncthreads();

  // ---- pure MFMA phase: no barriers ----
  const int lane  = tid & 63;
  const int wv    = tid >> 6;          // 0..7 (uniform per wave)
  const bool is1o = (wv < 6);
  const int q00   = (wv & 1) * 128;
  const int mbase = (is1o ? wv : (wv - 6)) * 128;
  const int lrow  = lane & 15;
  const int lgr   = lane >> 4;

  f32x4 acc[8][4] = {};

  if (is1o) {
    const float* __restrict__ U3r[8];
    #pragma unroll
    for (int mf = 0; mf < 8; ++mf)
      U3r[mf] = U3_1o + (size_t)(mbase + mf * 16 + lrow) * 528 + lgr * 8;
    #pragma unroll 2
    for (int t = 0; t < 16; ++t) {
      short8 af[8];
      #pragma unroll
      for (int mf = 0; mf < 8; ++mf) {
        f32x4 a  = *(const f32x4*)(U3r[mf] + t * 32);
        f32x4 bq = *(const f32x4*)(U3r[mf] + t * 32 + 4);
        af[mf] = pack8(a[0], a[1], a[2], a[3], bq[0], bq[1], bq[2], bq[3]);
      }
      short8 bfr[4];
      #pragma unroll
      for (int nf = 0; nf < 4; ++nf)
        bfr[nf] = *(const short8*)&B1buf[nf * 16 + lrow][t * 32 + lgr * 8];
      #pragma unroll
      for (int mf = 0; mf < 8; ++mf)
        #pragma unroll
        for (int nf = 0; nf < 4; ++nf)
          acc[mf][nf] = __builtin_amdgcn_mfma_f32_16x16x32_bf16(af[mf], bfr[nf], acc[mf][nf], 0, 0, 0);
    }
    {   // tail t=16: kap 512..543 = U3 cols 512..527 | U2[0..5] | zeros
      short8 af[8];
      #pragma unroll
      for (int mf = 0; mf < 8; ++mf) {
        const int row = mbase + mf * 16 + lrow;
        if (lgr < 2) {
          const float* p = U3_1o + (size_t)row * 528 + 512 + lgr * 8;
          f32x4 a = *(const f32x4*)p; f32x4 bq = *(const f32x4*)(p + 4);
          af[mf] = pack8(a[0], a[1], a[2], a[3], bq[0], bq[1], bq[2], bq[3]);
        } else if (lgr == 2) {
          const float* p = U2_1o + row * 6;
          af[mf] = pack8(p[0], p[1], p[2], p[3], p[4], p[5], 0.f, 0.f);
        } else {
          af[mf] = short8{0, 0, 0, 0, 0, 0, 0, 0};
        }
      }
      short8 bfr[4];
      #pragma unroll
      for (int nf = 0; nf < 4; ++nf)
        bfr[nf] = *(const short8*)&B1buf[nf * 16 + lrow][512 + lgr * 8];
      #pragma unroll
      for (int mf = 0; mf < 8; ++mf)
        #pragma unroll
        for (int nf = 0; nf < 4; ++nf)
          acc[mf][nf] = __builtin_amdgcn_mfma_f32_16x16x32_bf16(af[mf], bfr[nf], acc[mf][nf], 0, 0, 0);
    }
  } else {
    const float* __restrict__ U3r[8];
    #pragma unroll
    for (int mf = 0; mf < 8; ++mf)
      U3r[mf] = U3_0e + (size_t)(mbase + mf * 16 + lrow) * 368 + lgr * 8;
    #pragma unroll 2
    for (int t = 0; t < 11; ++t) {
      short8 af[8];
      #pragma unroll
      for (int mf = 0; mf < 8; ++mf) {
        f32x4 a  = *(const f32x4*)(U3r[mf] + t * 32);
        f32x4 bq = *(const f32x4*)(U3r[mf] + t * 32 + 4);
        af[mf] = pack8(a[0], a[1], a[2], a[3], bq[0], bq[1], bq[2], bq[3]);
      }
      short8 bfr[4];
      #pragma unroll
      for (int nf = 0; nf < 4; ++nf)
        bfr[nf] = *(const short8*)&B0buf[nf * 16 + lrow][t * 32 + lgr * 8];
      #pragma unroll
      for (int mf = 0; mf < 8; ++mf)
        #pragma unroll
        for (int nf = 0; nf < 4; ++nf)
          acc[mf][nf] = __builtin_amdgcn_mfma_f32_16x16x32_bf16(af[mf], bfr[nf], acc[mf][nf], 0, 0, 0);
    }
    {   // tail t=11: kap 352..383 = U3 cols 352..367 | U2[0..3] | zeros
      short8 af[8];
      #pragma unroll
      for (int mf = 0; mf < 8; ++mf) {
        const int row = mbase + mf * 16 + lrow;
        if (lgr < 2) {
          const float* p = U3_0e + (size_t)row * 368 + 352 + lgr * 8;
          f32x4 a = *(const f32x4*)p; f32x4 bq = *(const f32x4*)(p + 4);
          af[mf] = pack8(a[0], a[1], a[2], a[3], bq[0], bq[1], bq[2], bq[3]);
        } else if (lgr == 2) {
          const float* p = U2_0e + row * 4;
          af[mf] = pack8(p[0], p[1], p[2], p[3], 0.f, 0.f, 0.f, 0.f);
        } else {
          af[mf] = short8{0, 0, 0, 0, 0, 0, 0, 0};
        }
      }
      short8 bfr[4];
      #pragma unroll
      for (int nf = 0; nf < 4; ++nf)
        bfr[nf] = *(const short8*)&B0buf[nf * 16 + lrow][352 + lgr * 8];
      #pragma unroll
      for (int mf = 0; mf < 8; ++mf)
        #pragma unroll
        for (int nf = 0; nf < 4; ++nf)
          acc[mf][nf] = __builtin_amdgcn_mfma_f32_16x16x32_bf16(af[mf], bfr[nf], acc[mf][nf], 0, 0, 0);
    }
  }

  // ---- epilogue: Q-fold + reduce over row-groups ----
  float s[4] = {0.f, 0.f, 0.f, 0.f};
  const int rg = lgr * 4;
  #pragma unroll
  for (int mf = 0; mf < 8; ++mf) {
    #pragma unroll
    for (int reg = 0; reg < 4; ++reg) {
      const int q  = q00 + mf * 16 + rg + reg;   // 0..255 within group
      const int qa = q >> 4, qb = q & 15;
      #pragma unroll
      for (int nf = 0; nf < 4; ++nf) {
        const int p = nf * 16 + lrow;
        s[nf] += acc[mf][nf][reg] * (x_lds[qa][p] * x_lds[qb][p]);
      }
    }
  }
  #pragma unroll
  for (int nf = 0; nf < 4; ++nf) {
    s[nf] += __shfl_xor(s[nf], 16);
    s[nf] += __shfl_xor(s[nf], 32);
  }
  if (lane < 16) {
    #pragma unroll
    for (int nf = 0; nf < 4; ++nf) red[wv][nf * 16 + lane] = s[nf];
  }
  __syncthreads();

  // ---- final combine + U1 terms + store ----
  if (tid < 256) {
    const int slot = tid >> 6;   // 0..2 = 1o w, 3 = 0e
    const int n    = tid & 63;
    const int cc   = ((blk & 1) << 6) + n;
    if (slot < 3) {
      float u1 = 0.f;
      #pragma unroll
      for (int xx = 0; xx < 16; ++xx) u1 += U1_1o[slot * 16 + xx] * x_lds[xx][n];
      out[(size_t)b * 512 + 128 + cc * 3 + slot] =
          red[2 * slot][n] + red[2 * slot + 1][n] + zbuf[Z11][n] * u1;
    } else {
      float u1 = 0.f;
      #pragma unroll
      for (int xx = 0; xx < 16; ++xx) u1 += U1_0e[xx] * x_lds[xx][n];
      out[(size_t)b * 512 + cc] =
          red[6][n] + red[7][n] + zbuf[Z10][n] * u1;
    }
  }
}

extern "C" void kernel_launch(void* const* d_in, const int* in_sizes, int n_in,
                              void* d_out, int out_size, void* d_ws, size_t ws_size,
                              hipStream_t stream) {
  const float* x     = (const float*)d_in[0];
  const float* y     = (const float*)d_in[1];
  const float* U1_0e = (const float*)d_in[2];
  const float* U2_0e = (const float*)d_in[3];
  const float* U3_0e = (const float*)d_in[4];
  const float* U1_1o = (const float*)d_in[5];
  const float* U2_1o = (const float*)d_in[6];
  const float* U3_1o = (const float*)d_in[7];
  const float* w1_0e = (const float*)d_in[8];
  const float* w2_0e = (const float*)d_in[9];
  const float* w3_0e = (const float*)d_in[10];
  const float* w1_1o = (const float*)d_in[11];
  const float* w2_1o = (const float*)d_in[12];
  const float* w3_1o = (const float*)d_in[13];
  (void)in_sizes; (void)n_in; (void)out_size; (void)d_ws; (void)ws_size;

  hipLaunchKernelGGL(symcon_mfma, dim3(256), dim3(512), 0, stream,
                     x, y, U1_0e, U2_0e, U3_0e, U1_1o, U2_1o, U3_1o,
                     w1_0e, w2_0e, w3_0e, w1_1o, w2_1o, w3_1o,
                     (float*)d_out);
}